// Round 20
// baseline (44.639 us; speedup 1.0000x reference)
//
#include <hip/hip_runtime.h>
#include <hip/hip_bf16.h>

typedef short bf16x8 __attribute__((ext_vector_type(8)));
typedef float f32x4  __attribute__((ext_vector_type(4)));
typedef unsigned int u32;
typedef unsigned int u32x4 __attribute__((ext_vector_type(4)));

constexpr int HW = 4096;   // 64*64 pixels
constexpr int CT = 31;     // time channels
constexpr int CZ = 32;     // hidden channels
constexpr int CP = 128;    // poi channels
constexpr int CO = 64;     // output channels

__device__ __forceinline__ u32 f2bfu(float x) {
    __hip_bfloat16 h = __float2bfloat16(x);
    return (u32)*reinterpret_cast<unsigned short*>(&h);
}

// ---------------- kernel 1: time MLP, 2 px/thread via float2 (r19, passed) ----------------
__global__ __launch_bounds__(256)
void time_mlp2(const float* __restrict__ tin,
               const float* __restrict__ wm,
               const float* __restrict__ bm,
               const float* __restrict__ wf,
               const float* __restrict__ bf,
               float* __restrict__ tbuf)
{
    const int gid = blockIdx.x * 256 + threadIdx.x;
    const int px  = gid * 2;
    const int b   = px >> 12;
    const float* tp = tin + (size_t)b * CT * HW + (px & (HW - 1));

    float2 tr[CT];
    #pragma unroll
    for (int c = 0; c < CT; ++c)
        tr[c] = *reinterpret_cast<const float2*>(tp + (size_t)c * HW);
    __builtin_amdgcn_sched_barrier(0);

    float ax = bf[0], ay = ax;
    #pragma unroll
    for (int k = 0; k < CZ; ++k) {
        float zx = bm[k], zy = zx;
        #pragma unroll
        for (int c = 0; c < CT; ++c) {
            const float w = wm[k * CT + c];
            zx = fmaf(w, tr[c].x, zx);
            zy = fmaf(w, tr[c].y, zy);
        }
        const float wk = wf[k];
        ax = fmaf(wk, fmaxf(zx, 0.f), ax);
        ay = fmaf(wk, fmaxf(zy, 0.f), ay);
    }
    float2 r; r.x = fmaxf(ax, 0.f); r.y = fmaxf(ay, 0.f);
    *reinterpret_cast<float2*>(tbuf + px) = r;
}

// ---------------- kernel 2: pipelined MFMA GEMM, raw-barrier double buffer ----------------
// Block = 2 strips of 64 px, LDS double-buffered (2 x 16 KiB bf16 [px][ch],
// XOR-swizzled, r19-verified). Strip-1 global loads are issued BEFORE barrier 1
// and stay in flight across it: manual lgkmcnt(0) + raw s_barrier (NOT
// __syncthreads -> no forced vmcnt(0) drain). grid = 1024 blocks.
__global__ __launch_bounds__(256)
void poi_gemm_pipe(const float* __restrict__ poi,
                   const float* __restrict__ tbuf,
                   const float* __restrict__ wc,
                   const float* __restrict__ bc,
                   float* __restrict__ out)
{
    __shared__ __align__(16) unsigned short s_poi[2][64 * CP];   // 2 x 16 KiB

    const int tid  = threadIdx.x;
    const int lane = tid & 63;
    const int m    = lane & 15;      // o within subtile (B/D col)
    const int g    = lane >> 4;      // 4-lane group (k-subrange / D row-group)
    const int wid  = tid >> 6;       // o-subtile id 0..3
    const int p2   = tid & 31;       // staging: px pair
    const int cg   = tid >> 5;       // staging: ch group

    // one-time weight fragment: ONE o-subtile = 16 VGPRs (layout verified r8+)
    bf16x8 wcf[4];
    #pragma unroll
    for (int kf = 0; kf < 4; ++kf)
      #pragma unroll
      for (int j = 0; j < 8; ++j)
        wcf[kf][j] = (short)f2bfu(wc[(wid * 16 + m) * CP + kf * 32 + g * 8 + j]);
    const float bcf = bc[wid * 16 + m];

    const int S0 = blockIdx.x * 2;   // this block's two strip ids (of 2048)

    float2 v[16];
    auto load_strip = [&](int S) {
        const int b = S >> 6, px0 = (S & 63) << 6;
        const float* src = poi + (size_t)b * CP * HW + (size_t)(cg * 16) * HW
                               + px0 + p2 * 2;
        #pragma unroll
        for (int j = 0; j < 16; ++j)
            v[j] = *reinterpret_cast<const float2*>(src + (size_t)j * HW);
    };
    auto cvt_write = [&](int buf) {                     // consumes v (waits vmcnt)
        u32 r0[8], r1[8];
        #pragma unroll
        for (int j = 0; j < 8; ++j) {
            r0[j] = f2bfu(v[2 * j].x) | (f2bfu(v[2 * j + 1].x) << 16);
            r1[j] = f2bfu(v[2 * j].y) | (f2bfu(v[2 * j + 1].y) << 16);
        }
        u32* lds = reinterpret_cast<u32*>(s_poi[buf]);
        const int swz = (p2 & 7) << 2;
        const int d0  = (2 * p2) * (CP / 2) + cg * 8;
        const int d1  = d0 + (CP / 2);
        u32x4 a0 = {r0[0], r0[1], r0[2], r0[3]};
        u32x4 a1 = {r0[4], r0[5], r0[6], r0[7]};
        u32x4 b0 = {r1[0], r1[1], r1[2], r1[3]};
        u32x4 b1 = {r1[4], r1[5], r1[6], r1[7]};
        *reinterpret_cast<u32x4*>(lds + ((d0    ) ^ swz)) = a0;
        *reinterpret_cast<u32x4*>(lds + ((d0 + 4) ^ swz)) = a1;
        *reinterpret_cast<u32x4*>(lds + ((d1    ) ^ swz)) = b0;
        *reinterpret_cast<u32x4*>(lds + ((d1 + 4) ^ swz)) = b1;
    };
    auto compute_store = [&](int S, int buf) {
        const int b = S >> 6, px0 = (S & 63) << 6;
        const float* tb = tbuf + (size_t)b * HW + px0;
        float* obase = out + (size_t)b * CO * HW + (size_t)(wid * 16 + m) * HW
                           + px0 + g * 4;
        const u32* lds = reinterpret_cast<const u32*>(s_poi[buf]);
        #pragma unroll
        for (int t = 0; t < 4; ++t) {
            const int p     = t * 16 + m;
            const int swzr  = ((p >> 1) & 7) << 2;
            const int dbase = p * (CP / 2);
            bf16x8 pfv[4];
            #pragma unroll
            for (int kf = 0; kf < 4; ++kf)
                pfv[kf] = *reinterpret_cast<const bf16x8*>(
                    lds + ((dbase + kf * 16 + g * 4) ^ swzr));   // ds_read_b128
            f32x4 a = {0.f, 0.f, 0.f, 0.f};
            #pragma unroll
            for (int kf = 0; kf < 4; ++kf)
                a = __builtin_amdgcn_mfma_f32_16x16x32_bf16(pfv[kf], wcf[kf], a, 0, 0, 0);
            const f32x4 tv = *reinterpret_cast<const f32x4*>(tb + t * 16 + g * 4);
            f32x4 r;
            #pragma unroll
            for (int q = 0; q < 4; ++q) r[q] = fmaf(tv[q], a[q], bcf);
            __builtin_nontemporal_store(r, reinterpret_cast<f32x4*>(obase + t * 16));
        }
    };

    // ---- pipelined schedule ----
    load_strip(S0);
    cvt_write(0);                         // waits vmcnt for strip-0 loads
    load_strip(S0 + 1);                   // strip-1 loads issued, stay in flight
    __builtin_amdgcn_sched_barrier(0);
    asm volatile("s_waitcnt lgkmcnt(0)" ::: "memory");   // ds_writes(buf0) done
    __builtin_amdgcn_s_barrier();         // raw: does NOT drain vmcnt
    __builtin_amdgcn_sched_barrier(0);
    compute_store(S0, 0);                 // overlaps strip-1 HBM latency
    cvt_write(1);                         // vmcnt wait largely elapsed
    asm volatile("s_waitcnt lgkmcnt(0)" ::: "memory");
    __builtin_amdgcn_s_barrier();
    __builtin_amdgcn_sched_barrier(0);
    compute_store(S0 + 1, 1);
}

extern "C" void kernel_launch(void* const* d_in, const int* in_sizes, int n_in,
                              void* d_out, int out_size, void* d_ws, size_t ws_size,
                              hipStream_t stream) {
    const float* poi = (const float*)d_in[0];
    const float* tin = (const float*)d_in[1];
    const float* wm  = (const float*)d_in[2];
    const float* bm  = (const float*)d_in[3];
    const float* wf  = (const float*)d_in[4];
    const float* bf  = (const float*)d_in[5];
    const float* wc  = (const float*)d_in[6];
    const float* bc  = (const float*)d_in[7];
    float* out  = (float*)d_out;
    float* tbuf = (float*)d_ws;                 // 131072 floats = 512 KiB

    hipLaunchKernelGGL(time_mlp2, dim3(256), dim3(256), 0, stream,
                       tin, wm, bm, wf, bf, tbuf);
    hipLaunchKernelGGL(poi_gemm_pipe, dim3(1024), dim3(256), 0, stream,
                       poi, tbuf, wc, bc, out);
}

// Round 21
// 38.392 us; speedup vs baseline: 1.1627x; 1.1627x over previous
//
#include <hip/hip_runtime.h>
#include <hip/hip_bf16.h>

typedef short bf16x8 __attribute__((ext_vector_type(8)));
typedef float f32x4  __attribute__((ext_vector_type(4)));

constexpr int HW = 4096;   // 64*64 pixels
constexpr int CT = 31;     // time channels
constexpr int CP = 128;    // poi channels
constexpr int CO = 64;     // output channels

__device__ __forceinline__ short f2bf(float x) {
    __hip_bfloat16 h = __float2bfloat16(x);
    return *reinterpret_cast<short*>(&h);
}

// Issue a global load NOW (compiler cannot sink/serialize volatile asm).
// Result must not be read before the matching s_waitcnt vmcnt().
__device__ __forceinline__ float async_load(const float* p) {
    float v;
    asm volatile("global_load_dword %0, %1, off" : "=v"(v) : "v"(p));
    return v;
}
#define VM_WAIT(n) asm volatile("s_waitcnt vmcnt(" #n ")" ::: "memory")
#define SBAR() __builtin_amdgcn_sched_barrier(0)

// mfma5 geometry (r16, verified: absmax 9.8e-4, ideal traffic) with the 40
// per-tile loads as inline-asm issued 40-deep:
//   issue tf(8)+pf(32) -> vmcnt(32) -> stage-1 MLP (pf in flight) ->
//   vmcnt(0) -> cvt+MFMA+epilogue.
// 40 x 256 B = 10 KB in flight per wave; ~12 waves/CU -> ~120 KB/CU >> the
// ~14 KB needed to saturate HBM. Counted waits safe: tf are the 8 oldest of
// the asm block; older ops (tile-0 stores, stragglers) retire first;
// sched_barrier(0) fences foreign vmem out of the counted window.
__global__ __launch_bounds__(256)
void poi_mfma7(const float* __restrict__ poi,
               const float* __restrict__ tin,
               const float* __restrict__ wm,
               const float* __restrict__ bm,
               const float* __restrict__ wf,
               const float* __restrict__ bf,
               const float* __restrict__ wc,
               const float* __restrict__ bc,
               float* __restrict__ out)
{
    const int lane = threadIdx.x & 63;
    const int m    = lane & 15;       // free index: o (B,D-col) / px (A-row)
    const int g    = lane >> 4;       // 4-lane group: k-subrange / D row-group
    const int wid  = threadIdx.x >> 6;
    const int oh   = (wid & 1) * 2;   // this wave's o-subtiles: s in {oh, oh+1}
    const int b    = blockIdx.x >> 6;                        // 64 blocks/image
    const int px0  = ((blockIdx.x & 63) << 6) + (wid >> 1) * 32;  // wave strip

    // ---------- one-time weight fragments (layout verified r8+) ----------
    bf16x8 wcf[2][4];                 // [o-subtile][k-frag], B operand
    #pragma unroll
    for (int s = 0; s < 2; ++s)
      #pragma unroll
      for (int kf = 0; kf < 4; ++kf)
        #pragma unroll
        for (int j = 0; j < 8; ++j)
          wcf[s][kf][j] = f2bf(wc[((oh + s) * 16 + m) * CP + kf * 32 + g * 8 + j]);

    bf16x8 wmf[2];                    // wm: 32x31 padded to 32x32 (A operand)
    #pragma unroll
    for (int t2 = 0; t2 < 2; ++t2)
      #pragma unroll
      for (int j = 0; j < 8; ++j) {
        const int c = g * 8 + j;
        wmf[t2][j] = (c < CT) ? f2bf(wm[(t2 * 16 + m) * CT + c]) : (short)0;
      }
    float wff[8]; f32x4 bmf[2]; float bcf[2];
    #pragma unroll
    for (int t2 = 0; t2 < 2; ++t2)
      #pragma unroll
      for (int r = 0; r < 4; ++r) {
        wff[t2 * 4 + r] = wf[t2 * 16 + g * 4 + r];
        bmf[t2][r]      = bm[t2 * 16 + g * 4 + r];
      }
    #pragma unroll
    for (int s = 0; s < 2; ++s) bcf[s] = bc[(oh + s) * 16 + m];
    const float bfv = bf[0];

    const float* tbase = tin + (size_t)b * CT * HW;
    const float* pbase = poi + (size_t)b * CP * HW;
    float*       obase = out + (size_t)b * CO * HW;

    #pragma unroll
    for (int t = 0; t < 2; ++t) {
        const int pxt = px0 + t * 16;
        const float* tb = tbase + pxt + m;
        const float* pb = pbase + pxt + m;

        // ---- issue ALL 40 loads as volatile asm (program-order, 40-deep) ----
        float tfr[8];
        #pragma unroll
        for (int j = 0; j < 8; ++j) {
            const int c  = g * 8 + j;
            const int cc = (c < CT) ? c : (CT - 1);      // clamp pad lane
            tfr[j] = async_load(tb + (size_t)cc * HW);
        }
        float pfr[32];
        #pragma unroll
        for (int kf = 0; kf < 4; ++kf)
          #pragma unroll
          for (int j = 0; j < 8; ++j)
            pfr[kf * 8 + j] = async_load(pb + (size_t)(kf * 32 + g * 8 + j) * HW);
        SBAR();
        VM_WAIT(32);                  // the 8 tf loads (oldest) have landed
        SBAR();

        // ---- stage 1 (pf still in flight): tval = relu(wf.relu(wm@t+bm)+bf) ----
        bf16x8 tf;
        #pragma unroll
        for (int j = 0; j < 8; ++j) {
            const int c = g * 8 + j;
            tf[j] = (c < CT) ? f2bf(tfr[j]) : (short)0;
        }
        f32x4 z0 = __builtin_amdgcn_mfma_f32_16x16x32_bf16(wmf[0], tf, bmf[0], 0, 0, 0);
        f32x4 z1 = __builtin_amdgcn_mfma_f32_16x16x32_bf16(wmf[1], tf, bmf[1], 0, 0, 0);
        float s1 = 0.f;
        #pragma unroll
        for (int r = 0; r < 4; ++r) {
            s1 = fmaf(fmaxf(z0[r], 0.f), wff[r],     s1);
            s1 = fmaf(fmaxf(z1[r], 0.f), wff[4 + r], s1);
        }
        s1 += __shfl_xor(s1, 16, 64);         // sum hidden across lane-groups
        s1 += __shfl_xor(s1, 32, 64);
        const float tval = fmaxf(s1 + bfv, 0.f);   // valid for px = pxt + m
        f32x4 tv;                                  // transpose to D-row layout
        #pragma unroll
        for (int r = 0; r < 4; ++r) tv[r] = __shfl(tval, g * 4 + r, 64);

        SBAR();
        VM_WAIT(0);                   // all 32 pf landed (latency mostly elapsed)
        SBAR();

        // ---- stage 2: A = poi (M=px), B = wc (N=o), K=128 in 4 MFMAs ----
        bf16x8 pfv[4];
        #pragma unroll
        for (int kf = 0; kf < 4; ++kf)
          #pragma unroll
          for (int j = 0; j < 8; ++j)
            pfv[kf][j] = f2bf(pfr[kf * 8 + j]);

        float* ob = obase + pxt + g * 4;           // lane's 4-px store base
        #pragma unroll
        for (int s = 0; s < 2; ++s) {
            f32x4 a = {0.f, 0.f, 0.f, 0.f};
            #pragma unroll
            for (int kf = 0; kf < 4; ++kf)
                a = __builtin_amdgcn_mfma_f32_16x16x32_bf16(pfv[kf], wcf[s][kf], a, 0, 0, 0);
            f32x4 v;
            #pragma unroll
            for (int r = 0; r < 4; ++r) v[r] = fmaf(tv[r], a[r], bcf[s]);
            __builtin_nontemporal_store(
                v, reinterpret_cast<f32x4*>(ob + (size_t)((oh + s) * 16 + m) * HW));
        }
    }
}

extern "C" void kernel_launch(void* const* d_in, const int* in_sizes, int n_in,
                              void* d_out, int out_size, void* d_ws, size_t ws_size,
                              hipStream_t stream) {
    const float* poi = (const float*)d_in[0];
    const float* tin = (const float*)d_in[1];
    const float* wm  = (const float*)d_in[2];
    const float* bm  = (const float*)d_in[3];
    const float* wf  = (const float*)d_in[4];
    const float* bf  = (const float*)d_in[5];
    const float* wc  = (const float*)d_in[6];
    const float* bc  = (const float*)d_in[7];
    float* out = (float*)d_out;

    // 32 images x 64 strips; block = 2 px-halves x 2 o-halves = 4 waves
    hipLaunchKernelGGL(poi_mfma7, dim3(2048), dim3(256), 0, stream,
                       poi, tin, wm, bm, wf, bf, wc, bc, out);
}